// Round 1
// baseline (2003.925 us; speedup 1.0000x reference)
//
#include <hip/hip_runtime.h>
#include <cmath>

#define B_ 32
#define T_ 2048
#define H_ 1024

#define BK 32
#define ASTR 68   // 64 tokens + pad (multiple of 4 for float4 LDS reads)
#define BSTR 132  // 128 h + pad (multiple of 4)

__global__ __launch_bounds__(256) void zero_kernel(float* __restrict__ p, int n) {
    int i = blockIdx.x * 256 + threadIdx.x;
    if (i < n) p[i] = 0.f;
}

// q[b,h] = sum_j Wq[h,j]*dec[b,j] + bq[h]
__global__ __launch_bounds__(256) void q_kernel(const float* __restrict__ dec,
                                                const float* __restrict__ Wq,
                                                const float* __restrict__ bq,
                                                float* __restrict__ q) {
    int b = blockIdx.x;
    int hc = blockIdx.y;  // 4 chunks of 256 h
    __shared__ float ds[H_];
    for (int i = threadIdx.x; i < H_; i += 256) ds[i] = dec[b * H_ + i];
    __syncthreads();
    int h = hc * 256 + threadIdx.x;
    const float4* w = (const float4*)(Wq + (size_t)h * H_);
    float acc = 0.f;
#pragma unroll 8
    for (int j = 0; j < H_ / 4; j++) {
        float4 v = w[j];
        acc += v.x * ds[4 * j] + v.y * ds[4 * j + 1] + v.z * ds[4 * j + 2] + v.w * ds[4 * j + 3];
    }
    q[b * H_ + h] = acc + bq[h];
}

// score[b,t] += sum_{h in tile} Wout[h] * tanh( enc[b,t,:].Wk[h,:] + bk[h] + q[b,h] )
// Tiled fp32 GEMM, 64 tokens x 128 h per block, BK=32, fused tanh/Wout epilogue.
__global__ __launch_bounds__(256) void score_kernel(const float* __restrict__ enc,
                                                    const float* __restrict__ Wk,
                                                    const float* __restrict__ bk,
                                                    const float* __restrict__ q,
                                                    const float* __restrict__ Wout,
                                                    float* __restrict__ score) {
    __shared__ __align__(16) float As[BK * ASTR];  // [k][tok], transposed on store
    __shared__ __align__(16) float Bs[BK * BSTR];  // [k][h]
    __shared__ float wout_s[128];
    __shared__ float kq_s[128];

    const int mt = blockIdx.x;          // 1024 token tiles
    const int nt = blockIdx.y;          // 8 h tiles
    const int m0 = mt * 64;
    const int h0 = nt * 128;
    const int b = m0 >> 11;             // T_=2048 tokens per b; tiles never cross b
    const int t0 = m0 & (T_ - 1);
    const int tid = threadIdx.x;
    const int tx = tid & 15;            // h dim: 16 groups
    const int ty = tid >> 4;            // tok dim: 16 groups of 4 tokens

    if (tid < 128) {
        wout_s[tid] = Wout[h0 + tid];
        kq_s[tid] = bk[h0 + tid] + q[b * H_ + h0 + tid];
    }

    float acc[4][8];
#pragma unroll
    for (int i = 0; i < 4; i++)
#pragma unroll
        for (int j = 0; j < 8; j++) acc[i][j] = 0.f;

    for (int k0 = 0; k0 < H_; k0 += BK) {
        __syncthreads();  // protect previous iteration's LDS reads (also covers wout_s/kq_s init)
        // stage A: 64 tokens x 32 k, transpose into As[k][tok]
#pragma unroll
        for (int r = 0; r < 2; r++) {
            int li = tid + r * 256;
            int tok = li >> 3, kg = li & 7;
            float4 v = *(const float4*)(enc + (size_t)(m0 + tok) * H_ + k0 + kg * 4);
            As[(kg * 4 + 0) * ASTR + tok] = v.x;
            As[(kg * 4 + 1) * ASTR + tok] = v.y;
            As[(kg * 4 + 2) * ASTR + tok] = v.z;
            As[(kg * 4 + 3) * ASTR + tok] = v.w;
        }
        // stage B: 128 h x 32 k, transpose into Bs[k][h]
#pragma unroll
        for (int r = 0; r < 4; r++) {
            int li = tid + r * 256;
            int h = li >> 3, kg = li & 7;
            float4 v = *(const float4*)(Wk + (size_t)(h0 + h) * H_ + k0 + kg * 4);
            Bs[(kg * 4 + 0) * BSTR + h] = v.x;
            Bs[(kg * 4 + 1) * BSTR + h] = v.y;
            Bs[(kg * 4 + 2) * BSTR + h] = v.z;
            Bs[(kg * 4 + 3) * BSTR + h] = v.w;
        }
        __syncthreads();
#pragma unroll
        for (int kk = 0; kk < BK; kk++) {
            float4 a4 = *(const float4*)&As[kk * ASTR + ty * 4];
            float4 b4a = *(const float4*)&Bs[kk * BSTR + tx * 4];
            float4 b4b = *(const float4*)&Bs[kk * BSTR + 64 + tx * 4];
            float av[4] = {a4.x, a4.y, a4.z, a4.w};
            float bv[8] = {b4a.x, b4a.y, b4a.z, b4a.w, b4b.x, b4b.y, b4b.z, b4b.w};
#pragma unroll
            for (int i = 0; i < 4; i++)
#pragma unroll
                for (int j = 0; j < 8; j++) acc[i][j] += av[i] * bv[j];
        }
    }

    // epilogue: partial score = sum_h wout[h]*tanh(acc + bk[h] + q[b,h])
    float wv[8], kqv[8];
#pragma unroll
    for (int j = 0; j < 8; j++) {
        int hl = (j < 4) ? (tx * 4 + j) : (64 + tx * 4 + (j - 4));
        wv[j] = wout_s[hl];
        kqv[j] = kq_s[hl];
    }
#pragma unroll
    for (int i = 0; i < 4; i++) {
        float s = 0.f;
#pragma unroll
        for (int j = 0; j < 8; j++) s += wv[j] * tanhf(acc[i][j] + kqv[j]);
        // reduce across the 16 tx lanes (lanes of same ty are consecutive within the wave)
#pragma unroll
        for (int m = 1; m < 16; m <<= 1) s += __shfl_xor(s, m, 64);
        if (tx == 0) atomicAdd(&score[b * T_ + t0 + ty * 4 + i], s);
    }
}

// in-place softmax over T for each b (bout omitted: softmax is shift-invariant)
__global__ __launch_bounds__(256) void softmax_kernel(float* __restrict__ score) {
    int b = blockIdx.x, tid = threadIdx.x;
    float* s = score + b * T_;
    __shared__ float red[8];
    float v[8];
    float mx = -1e30f;
#pragma unroll
    for (int i = 0; i < 8; i++) {
        v[i] = s[tid + i * 256];
        mx = fmaxf(mx, v[i]);
    }
#pragma unroll
    for (int m = 32; m >= 1; m >>= 1) mx = fmaxf(mx, __shfl_xor(mx, m, 64));
    if ((tid & 63) == 0) red[tid >> 6] = mx;
    __syncthreads();
    mx = fmaxf(fmaxf(red[0], red[1]), fmaxf(red[2], red[3]));
    float sum = 0.f;
#pragma unroll
    for (int i = 0; i < 8; i++) {
        v[i] = __expf(v[i] - mx);
        sum += v[i];
    }
#pragma unroll
    for (int m = 32; m >= 1; m >>= 1) sum += __shfl_xor(sum, m, 64);
    if ((tid & 63) == 0) red[4 + (tid >> 6)] = sum;
    __syncthreads();
    sum = red[4] + red[5] + red[6] + red[7];
    float inv = 1.f / sum;
#pragma unroll
    for (int i = 0; i < 8; i++) s[tid + i * 256] = v[i] * inv;
}

// context[b,h] = sum_t attn[b,t]*enc[b,t,h]; grid (tsplit=16, hchunk=4, b=32)
__global__ __launch_bounds__(256) void context_kernel(const float* __restrict__ enc,
                                                      const float* __restrict__ attn,
                                                      float* __restrict__ out) {
    int ts = blockIdx.x, hc = blockIdx.y, b = blockIdx.z;
    int h = hc * 256 + threadIdx.x;
    const float* e = enc + (size_t)b * T_ * H_ + (size_t)ts * 128 * H_ + h;
    const float* a = attn + b * T_ + ts * 128;
    float acc = 0.f;
#pragma unroll 4
    for (int t = 0; t < 128; t++) acc += a[t] * e[(size_t)t * H_];
    atomicAdd(&out[b * H_ + h], acc);
}

extern "C" void kernel_launch(void* const* d_in, const int* in_sizes, int n_in,
                              void* d_out, int out_size, void* d_ws, size_t ws_size,
                              hipStream_t stream) {
    const float* enc = (const float*)d_in[0];
    const float* dec = (const float*)d_in[1];   // [1,B,H] -> flat b*H+h
    const float* Wk = (const float*)d_in[2];
    const float* bk = (const float*)d_in[3];
    const float* Wq = (const float*)d_in[4];
    const float* bq = (const float*)d_in[5];
    const float* Wout = (const float*)d_in[6];
    // d_in[7] = bout: cancels under softmax. d_in[8] = inputs: unused.
    float* out = (float*)d_out;

    float* q = (float*)d_ws;          // B_*H_ floats
    float* score = q + B_ * H_;       // B_*T_ floats (attn in-place after softmax)

    zero_kernel<<<(B_ * T_ + 255) / 256, 256, 0, stream>>>(score, B_ * T_);
    zero_kernel<<<(B_ * H_ + 255) / 256, 256, 0, stream>>>(out, B_ * H_);
    q_kernel<<<dim3(B_, 4), 256, 0, stream>>>(dec, Wq, bq, q);
    score_kernel<<<dim3(1024, 8), 256, 0, stream>>>(enc, Wk, bk, q, Wout, score);
    softmax_kernel<<<B_, 256, 0, stream>>>(score);
    context_kernel<<<dim3(16, 4, B_), 256, 0, stream>>>(enc, score, out);
}

// Round 2
// 761.205 us; speedup vs baseline: 2.6326x; 2.6326x over previous
//
#include <hip/hip_runtime.h>
#include <cmath>
#include <stdint.h>

#define B_ 32
#define T_ 2048
#define H_ 1024

typedef __attribute__((ext_vector_type(8))) __bf16 bf16x8;
typedef __attribute__((ext_vector_type(4))) float f32x4;

__device__ inline void async_copy16(const void* g, void* l) {
    __builtin_amdgcn_global_load_lds((const __attribute__((address_space(1))) uint32_t*)g,
                                     (__attribute__((address_space(3))) uint32_t*)l, 16, 0, 0);
}

__device__ inline float fast_tanh(float x) {
    float e = __expf(2.f * x);
    return 1.f - 2.f / (e + 1.f);
}

__global__ __launch_bounds__(256) void zero_kernel(float* __restrict__ p, int n) {
    int i = blockIdx.x * 256 + threadIdx.x;
    if (i < n) p[i] = 0.f;
}

// fp32 -> bf16, 8 elements per thread; n must be a multiple of 2048 per grid sizing
__global__ __launch_bounds__(256) void convert_kernel(const float* __restrict__ in,
                                                      __bf16* __restrict__ out) {
    size_t i = (size_t)(blockIdx.x * 256 + threadIdx.x) * 8;
    const float4* p = (const float4*)(in + i);
    float4 v0 = p[0], v1 = p[1];
    bf16x8 o;
    o[0] = (__bf16)v0.x; o[1] = (__bf16)v0.y; o[2] = (__bf16)v0.z; o[3] = (__bf16)v0.w;
    o[4] = (__bf16)v1.x; o[5] = (__bf16)v1.y; o[6] = (__bf16)v1.z; o[7] = (__bf16)v1.w;
    *(bf16x8*)(out + i) = o;
}

// kq[b,h] = sum_j Wq[h,j]*dec[b,j] + bq[h] + bk[h]
__global__ __launch_bounds__(256) void q_kernel(const float* __restrict__ dec,
                                                const float* __restrict__ Wq,
                                                const float* __restrict__ bq,
                                                const float* __restrict__ bk,
                                                float* __restrict__ kq) {
    int b = blockIdx.x;
    int hc = blockIdx.y;
    __shared__ float ds[H_];
    for (int i = threadIdx.x; i < H_; i += 256) ds[i] = dec[b * H_ + i];
    __syncthreads();
    int h = hc * 256 + threadIdx.x;
    const float4* w = (const float4*)(Wq + (size_t)h * H_);
    float acc = 0.f;
#pragma unroll 8
    for (int j = 0; j < H_ / 4; j++) {
        float4 v = w[j];
        acc += v.x * ds[4 * j] + v.y * ds[4 * j + 1] + v.z * ds[4 * j + 2] + v.w * ds[4 * j + 3];
    }
    kq[b * H_ + h] = acc + bq[h] + bk[h];
}

// MFMA score GEMM: score[b,t] += sum_h Wout[h]*tanh(enc[t,:]·Wk[h,:] + kq[b,h])
// 128x128 tile, BK=32, 16x16x32 bf16 MFMA, 4 waves in 2x2, 4x4 frags/wave.
// LDS chunk layout [kgroup][row] so ds_read_b128 is <=2-way bank-aliased.
__global__ __launch_bounds__(256) void score_mfma(const __bf16* __restrict__ encb,
                                                  const __bf16* __restrict__ Wkb,
                                                  const float* __restrict__ kq,
                                                  const float* __restrict__ Wout,
                                                  float* __restrict__ score) {
    __shared__ __align__(16) __bf16 As[512 * 8];  // 8 KB: 4 kgroups x 128 tokens x 8 bf16
    __shared__ __align__(16) __bf16 Bs[512 * 8];  // 8 KB: 4 kgroups x 128 h x 8 bf16

    const int h0 = blockIdx.x * 128;   // grid.x = 8 -> XCD affinity for Wkb L2 residency
    const int m0 = blockIdx.y * 128;
    const int b = m0 >> 11;            // 2048 tokens per b; 128 | 2048, never crosses
    const int tid = threadIdx.x;
    const int lane = tid & 63;
    const int w = tid >> 6;
    const int wm = w & 1, wn = w >> 1;
    const int q4 = lane >> 4, l15 = lane & 15;

    // staging slots: S = w*128 + r*64 + lane, chunk index == S, LDS off = S*16B
    const int S0 = w * 128 + lane;
    const int S1 = S0 + 64;
    const int kg0 = S0 >> 7, row0 = S0 & 127;
    const int kg1 = S1 >> 7, row1 = S1 & 127;
    const __bf16* gA0 = encb + (size_t)(m0 + row0) * H_ + kg0 * 8;
    const __bf16* gA1 = encb + (size_t)(m0 + row1) * H_ + kg1 * 8;
    const __bf16* gB0 = Wkb + (size_t)(h0 + row0) * H_ + kg0 * 8;
    const __bf16* gB1 = Wkb + (size_t)(h0 + row1) * H_ + kg1 * 8;
    __bf16* lA0 = As + (size_t)(w * 128) * 8;          // wave-uniform bases
    __bf16* lA1 = As + (size_t)(w * 128 + 64) * 8;
    __bf16* lB0 = Bs + (size_t)(w * 128) * 8;
    __bf16* lB1 = Bs + (size_t)(w * 128 + 64) * 8;

    f32x4 acc[4][4];
#pragma unroll
    for (int i = 0; i < 4; i++)
#pragma unroll
        for (int j = 0; j < 4; j++) acc[i][j] = (f32x4){0.f, 0.f, 0.f, 0.f};

    for (int k0 = 0; k0 < H_; k0 += 32) {
        __syncthreads();
        async_copy16(gA0 + k0, lA0);
        async_copy16(gA1 + k0, lA1);
        async_copy16(gB0 + k0, lB0);
        async_copy16(gB1 + k0, lB1);
        __syncthreads();  // compiler emits vmcnt(0) drain before s_barrier

        bf16x8 a[4], bb[4];
#pragma unroll
        for (int mf = 0; mf < 4; mf++)
            a[mf] = *(const bf16x8*)(As + (size_t)(q4 * 128 + wm * 64 + mf * 16 + l15) * 8);
#pragma unroll
        for (int nf = 0; nf < 4; nf++)
            bb[nf] = *(const bf16x8*)(Bs + (size_t)(q4 * 128 + wn * 64 + nf * 16 + l15) * 8);
#pragma unroll
        for (int mf = 0; mf < 4; mf++)
#pragma unroll
            for (int nf = 0; nf < 4; nf++)
                acc[mf][nf] = __builtin_amdgcn_mfma_f32_16x16x32_bf16(a[mf], bb[nf], acc[mf][nf], 0, 0, 0);
    }

    // epilogue: per row, sum_h wout[h]*tanh(K + kq) over this wave's 64 columns
    float wv[4], kqv[4];
#pragma unroll
    for (int nf = 0; nf < 4; nf++) {
        int h = h0 + wn * 64 + nf * 16 + l15;
        wv[nf] = Wout[h];
        kqv[nf] = kq[b * H_ + h];
    }
#pragma unroll
    for (int mf = 0; mf < 4; mf++) {
#pragma unroll
        for (int r = 0; r < 4; r++) {
            float s = 0.f;
#pragma unroll
            for (int nf = 0; nf < 4; nf++)
                s += wv[nf] * fast_tanh(acc[mf][nf][r] + kqv[nf]);
#pragma unroll
            for (int m = 1; m < 16; m <<= 1) s += __shfl_xor(s, m, 64);
            if (l15 == 0)
                atomicAdd(&score[m0 + wm * 64 + mf * 16 + q4 * 4 + r], s);
        }
    }
}

// ---------- fp32 fallback score path (used only if ws too small) ----------
#define BK 32
#define ASTR 68
#define BSTR 132
__global__ __launch_bounds__(256) void score_fp32(const float* __restrict__ enc,
                                                  const float* __restrict__ Wk,
                                                  const float* __restrict__ kq,
                                                  const float* __restrict__ Wout,
                                                  float* __restrict__ score) {
    __shared__ __align__(16) float As[BK * ASTR];
    __shared__ __align__(16) float Bs[BK * BSTR];
    __shared__ float wout_s[128];
    __shared__ float kq_s[128];
    const int m0 = blockIdx.x * 64;
    const int h0 = blockIdx.y * 128;
    const int b = m0 >> 11;
    const int tid = threadIdx.x;
    const int tx = tid & 15;
    const int ty = tid >> 4;
    if (tid < 128) {
        wout_s[tid] = Wout[h0 + tid];
        kq_s[tid] = kq[b * H_ + h0 + tid];
    }
    float acc[4][8];
#pragma unroll
    for (int i = 0; i < 4; i++)
#pragma unroll
        for (int j = 0; j < 8; j++) acc[i][j] = 0.f;
    for (int k0 = 0; k0 < H_; k0 += BK) {
        __syncthreads();
#pragma unroll
        for (int r = 0; r < 2; r++) {
            int li = tid + r * 256;
            int tok = li >> 3, kg = li & 7;
            float4 v = *(const float4*)(enc + (size_t)(m0 + tok) * H_ + k0 + kg * 4);
            As[(kg * 4 + 0) * ASTR + tok] = v.x;
            As[(kg * 4 + 1) * ASTR + tok] = v.y;
            As[(kg * 4 + 2) * ASTR + tok] = v.z;
            As[(kg * 4 + 3) * ASTR + tok] = v.w;
        }
#pragma unroll
        for (int r = 0; r < 4; r++) {
            int li = tid + r * 256;
            int h = li >> 3, kg = li & 7;
            float4 v = *(const float4*)(Wk + (size_t)(h0 + h) * H_ + k0 + kg * 4);
            Bs[(kg * 4 + 0) * BSTR + h] = v.x;
            Bs[(kg * 4 + 1) * BSTR + h] = v.y;
            Bs[(kg * 4 + 2) * BSTR + h] = v.z;
            Bs[(kg * 4 + 3) * BSTR + h] = v.w;
        }
        __syncthreads();
#pragma unroll
        for (int kk = 0; kk < BK; kk++) {
            float4 a4 = *(const float4*)&As[kk * ASTR + ty * 4];
            float4 b4a = *(const float4*)&Bs[kk * BSTR + tx * 4];
            float4 b4b = *(const float4*)&Bs[kk * BSTR + 64 + tx * 4];
            float av[4] = {a4.x, a4.y, a4.z, a4.w};
            float bv[8] = {b4a.x, b4a.y, b4a.z, b4a.w, b4b.x, b4b.y, b4b.z, b4b.w};
#pragma unroll
            for (int i = 0; i < 4; i++)
#pragma unroll
                for (int j = 0; j < 8; j++) acc[i][j] += av[i] * bv[j];
        }
    }
    float wv[8], kqv[8];
#pragma unroll
    for (int j = 0; j < 8; j++) {
        int hl = (j < 4) ? (tx * 4 + j) : (64 + tx * 4 + (j - 4));
        wv[j] = wout_s[hl];
        kqv[j] = kq_s[hl];
    }
#pragma unroll
    for (int i = 0; i < 4; i++) {
        float s = 0.f;
#pragma unroll
        for (int j = 0; j < 8; j++) s += wv[j] * tanhf(acc[i][j] + kqv[j]);
#pragma unroll
        for (int m = 1; m < 16; m <<= 1) s += __shfl_xor(s, m, 64);
        if (tx == 0) atomicAdd(&score[m0 + ty * 4 + i], s);
    }
}
// --------------------------------------------------------------------------

__global__ __launch_bounds__(256) void softmax_kernel(float* __restrict__ score) {
    int b = blockIdx.x, tid = threadIdx.x;
    float* s = score + b * T_;
    __shared__ float red[8];
    float v[8];
    float mx = -1e30f;
#pragma unroll
    for (int i = 0; i < 8; i++) {
        v[i] = s[tid + i * 256];
        mx = fmaxf(mx, v[i]);
    }
#pragma unroll
    for (int m = 32; m >= 1; m >>= 1) mx = fmaxf(mx, __shfl_xor(mx, m, 64));
    if ((tid & 63) == 0) red[tid >> 6] = mx;
    __syncthreads();
    mx = fmaxf(fmaxf(red[0], red[1]), fmaxf(red[2], red[3]));
    float sum = 0.f;
#pragma unroll
    for (int i = 0; i < 8; i++) {
        v[i] = __expf(v[i] - mx);
        sum += v[i];
    }
#pragma unroll
    for (int m = 32; m >= 1; m >>= 1) sum += __shfl_xor(sum, m, 64);
    if ((tid & 63) == 0) red[4 + (tid >> 6)] = sum;
    __syncthreads();
    sum = red[4] + red[5] + red[6] + red[7];
    float inv = 1.f / sum;
#pragma unroll
    for (int i = 0; i < 8; i++) s[tid + i * 256] = v[i] * inv;
}

// context[b,h] = sum_t attn[b,t]*enc[b,t,h]; fp32 enc for accuracy. grid (32 tsplit, B)
__global__ __launch_bounds__(256) void context_kernel(const float* __restrict__ enc,
                                                      const float* __restrict__ attn,
                                                      float* __restrict__ out) {
    int ts = blockIdx.x, b = blockIdx.y;
    const float* e = enc + (size_t)b * T_ * H_ + (size_t)ts * 64 * H_ + threadIdx.x * 4;
    const float* a = attn + b * T_ + ts * 64;
    float4 acc = {0.f, 0.f, 0.f, 0.f};
#pragma unroll 4
    for (int t = 0; t < 64; t++) {
        float av = a[t];
        float4 v = *(const float4*)(e + (size_t)t * H_);
        acc.x += av * v.x; acc.y += av * v.y; acc.z += av * v.z; acc.w += av * v.w;
    }
    float* o = out + b * H_ + threadIdx.x * 4;
    atomicAdd(o + 0, acc.x);
    atomicAdd(o + 1, acc.y);
    atomicAdd(o + 2, acc.z);
    atomicAdd(o + 3, acc.w);
}

extern "C" void kernel_launch(void* const* d_in, const int* in_sizes, int n_in,
                              void* d_out, int out_size, void* d_ws, size_t ws_size,
                              hipStream_t stream) {
    const float* enc = (const float*)d_in[0];
    const float* dec = (const float*)d_in[1];
    const float* Wk = (const float*)d_in[2];
    const float* bk = (const float*)d_in[3];
    const float* Wq = (const float*)d_in[4];
    const float* bq = (const float*)d_in[5];
    const float* Wout = (const float*)d_in[6];
    // d_in[7] = bout: cancels under softmax. d_in[8] = inputs: unused.
    float* out = (float*)d_out;

    const size_t encb_bytes = (size_t)B_ * T_ * H_ * 2;   // 134217728
    const size_t wkb_bytes = (size_t)H_ * H_ * 2;         // 2097152
    const size_t need = encb_bytes + wkb_bytes + (size_t)B_ * H_ * 4 + (size_t)B_ * T_ * 4;

    if (ws_size >= need) {
        __bf16* encb = (__bf16*)d_ws;
        __bf16* Wkb = (__bf16*)((char*)d_ws + encb_bytes);
        float* kq = (float*)((char*)d_ws + encb_bytes + wkb_bytes);
        float* score = kq + B_ * H_;

        convert_kernel<<<(B_ * T_ * H_) / 2048, 256, 0, stream>>>(enc, encb);
        convert_kernel<<<(H_ * H_) / 2048, 256, 0, stream>>>(Wk, Wkb);
        q_kernel<<<dim3(B_, 4), 256, 0, stream>>>(dec, Wq, bq, bk, kq);
        zero_kernel<<<(B_ * T_ + 255) / 256, 256, 0, stream>>>(score, B_ * T_);
        zero_kernel<<<(B_ * H_ + 255) / 256, 256, 0, stream>>>(out, B_ * H_);
        score_mfma<<<dim3(8, 512), 256, 0, stream>>>(encb, Wkb, kq, Wout, score);
        softmax_kernel<<<B_, 256, 0, stream>>>(score);
        context_kernel<<<dim3(32, B_), 256, 0, stream>>>(enc, score, out);
    } else {
        float* kq = (float*)d_ws;
        float* score = kq + B_ * H_;
        q_kernel<<<dim3(B_, 4), 256, 0, stream>>>(dec, Wq, bq, bk, kq);
        zero_kernel<<<(B_ * T_ + 255) / 256, 256, 0, stream>>>(score, B_ * T_);
        zero_kernel<<<(B_ * H_ + 255) / 256, 256, 0, stream>>>(out, B_ * H_);
        score_fp32<<<dim3(1024, 8), 256, 0, stream>>>(enc, Wk, kq, Wout, score);
        softmax_kernel<<<B_, 256, 0, stream>>>(score);
        context_kernel<<<dim3(32, B_), 256, 0, stream>>>(enc, score, out);
    }
}